// Round 4
// baseline (25.366 us; speedup 1.0000x reference)
//
#include <hip/hip_runtime.h>

// CustomEmbedding: out[t, :] = sin-row if x[t] < 1000 else weight[x[t], :]
// D = 512 floats -> 128 float4/token, one float4 per thread per chain.
// UNROLL=4 independent token chains per thread for memory-level parallelism:
// the single dependent chain (idx load -> row load -> store) was latency-bound.

#define DIM 512
#define NUM_NUM 1000
#define UNROLL 4

typedef float floatx4 __attribute__((ext_vector_type(4)));

__global__ __launch_bounds__(256) void CustomEmbedding_kernel(
    const int* __restrict__ x,
    const float* __restrict__ weight,
    float* __restrict__ out,
    int n_tok)
{
    int gid  = blockIdx.x * 256 + threadIdx.x;
    int tok0 = gid >> 7;                 // base token for chain 0
    int d4   = gid & 127;                // float4 index within the row
    int chunk = (n_tok + UNROLL - 1) / UNROLL;   // 8192 for n_tok=32768
    if (tok0 >= chunk) return;
    int d = d4 << 2;

    int   toks[UNROLL];
    int   idxs[UNROLL];
    floatx4 v[UNROLL];

    #pragma unroll
    for (int u = 0; u < UNROLL; ++u)
        toks[u] = tok0 + u * chunk;

    // 1) all index loads in flight (independent)
    #pragma unroll
    for (int u = 0; u < UNROLL; ++u)
        idxs[u] = (toks[u] < n_tok) ? x[toks[u]] : 0;

    // 2) all row loads in flight (each depends only on its own idx;
    //    always valid since idx < 50000, numeric rows add ~1.3 MB fetch)
    #pragma unroll
    for (int u = 0; u < UNROLL; ++u)
        v[u] = *reinterpret_cast<const floatx4*>(
                   weight + (size_t)idxs[u] * DIM + d);

    // 3) overwrite with sinusoidal row where numeric (wave-uniform branch)
    #pragma unroll
    for (int u = 0; u < UNROLL; ++u) {
        if (idxs[u] < NUM_NUM) {
            float base = (float)idxs[u] * 1e-3f;
            v[u].x = sinf(base * (float)(d + 1));
            v[u].y = sinf(base * (float)(d + 2));
            v[u].z = sinf(base * (float)(d + 3));
            v[u].w = sinf(base * (float)(d + 4));
        }
    }

    // 4) nontemporal streaming stores
    #pragma unroll
    for (int u = 0; u < UNROLL; ++u)
        if (toks[u] < n_tok)
            __builtin_nontemporal_store(
                v[u], reinterpret_cast<floatx4*>(out + (size_t)toks[u] * DIM + d));
}

extern "C" void kernel_launch(void* const* d_in, const int* in_sizes, int n_in,
                              void* d_out, int out_size, void* d_ws, size_t ws_size,
                              hipStream_t stream) {
    const int*   x      = (const int*)d_in[0];
    const float* weight = (const float*)d_in[1];
    // d_in[2] (num_value) and d_in[3] (is_num) are pure functions of the id; unused.
    float* out = (float*)d_out;

    int n_tok = in_sizes[0];                         // 8 * 4096 = 32768
    int chunk = (n_tok + UNROLL - 1) / UNROLL;       // tokens per chain slot
    long long total_threads = (long long)chunk * 128;
    int grid = (int)((total_threads + 255) / 256);   // 4096 blocks
    CustomEmbedding_kernel<<<grid, 256, 0, stream>>>(x, weight, out, n_tok);
}

// Round 5
// 25.237 us; speedup vs baseline: 1.0051x; 1.0051x over previous
//
#include <hip/hip_runtime.h>

// CustomEmbedding: out[t, :] = sin-row if x[t] < 1000 else weight[x[t], :]
// Grid-stride persistent kernel: 2048 blocks x 256 = 32 waves/CU resident
// (G11: cap grid ~2048 for memory-bound, stride the rest). One float4 per
// thread-iteration; nt stores for the write-once output.

#define DIM 512
#define NUM_NUM 1000
#define GRID_BLOCKS 2048

typedef float floatx4 __attribute__((ext_vector_type(4)));

__global__ __launch_bounds__(256) void CustomEmbedding_kernel(
    const int* __restrict__ x,
    const float* __restrict__ weight,
    float* __restrict__ out,
    long long total)                       // n_tok * 128 float4 slots
{
    long long stride = (long long)gridDim.x * 256;
    for (long long i = blockIdx.x * 256LL + threadIdx.x; i < total; i += stride) {
        int tok = (int)(i >> 7);
        int d   = ((int)i & 127) << 2;     // float index within the row

        int idx = x[tok];                  // broadcast within the token's lanes
        floatx4 v;
        if (idx < NUM_NUM) {               // wave-uniform (all lanes share tok's idx)
            float base = (float)idx * 1e-3f;
            v.x = sinf(base * (float)(d + 1));
            v.y = sinf(base * (float)(d + 2));
            v.z = sinf(base * (float)(d + 3));
            v.w = sinf(base * (float)(d + 4));
        } else {
            v = *reinterpret_cast<const floatx4*>(weight + (size_t)idx * DIM + d);
        }
        __builtin_nontemporal_store(v, reinterpret_cast<floatx4*>(out + (i << 2)));
    }
}

extern "C" void kernel_launch(void* const* d_in, const int* in_sizes, int n_in,
                              void* d_out, int out_size, void* d_ws, size_t ws_size,
                              hipStream_t stream) {
    const int*   x      = (const int*)d_in[0];
    const float* weight = (const float*)d_in[1];
    // d_in[2] (num_value) and d_in[3] (is_num) are pure functions of the id; unused.
    float* out = (float*)d_out;

    int n_tok = in_sizes[0];                        // 8 * 4096 = 32768
    long long total = (long long)n_tok * 128;       // float4 slots
    long long need  = (total + 255) / 256;
    int grid = (int)(need < GRID_BLOCKS ? need : GRID_BLOCKS);
    CustomEmbedding_kernel<<<grid, 256, 0, stream>>>(x, weight, out, total);
}